// Round 7
// baseline (719.967 us; speedup 1.0000x reference)
//
#include <hip/hip_runtime.h>
#include <hip/hip_cooperative_groups.h>

namespace cg = cooperative_groups;

#define NN 100000
#define NE 1600000
#define D 64
#define BKT_SHIFT 6
#define BKT_NODES 64
#define BKT_MASK 63
#define NBKT 1563           // ceil(NN / 64) buckets of 64 nodes
#define SRC_MASK 0x1FFFF    // src < 100000 < 2^17
#define EPB 8192            // edges per p2 block (196 blocks, 32 edges/thread)
#define NPB ((NE + EPB - 1) / EPB)   // 196
#define BINCAP 1280         // mean 1024, sd ~32 -> 8 sigma
#define TROWS 16            // rows per transform tile
#define NTILE (NN / TROWS)  // 6250 exact
#define TCHUNK 8            // tiles per transform work-claim (mono)
#define NCHUNKT ((NTILE + TCHUNK - 1) / TCHUNK)  // 782
#define TGRID 2048          // transform blocks in fallback fused kernel
#define GRID 1024           // mono: co-resident 4 blocks/CU x 256 CU

// float -> bf16 (round-to-nearest-even; inputs finite)
__device__ __forceinline__ unsigned short f2bf(float f) {
    unsigned u = __float_as_uint(f);
    unsigned r = u + 0x7FFF + ((u >> 16) & 1);
    return (unsigned short)(r >> 16);
}

__device__ __forceinline__ int cmp4(const int4& v, int k) {
    return k == 0 ? v.x : k == 1 ? v.y : k == 2 ? v.z : v.w;
}

// ======================= mono (cooperative, preferred) =====================
// Round-5 failure diagnosis: per-XCD L2s are NOT coherent and grid.sync()
// does not invalidate them.  Under graph replay, phase-2 readers can hit
// clean-but-stale hb/binned/cursor lines cached by their XCD in the PREVIOUS
// iteration.  Fix: __threadfence() (agent-scope: L2 writeback / invalidate)
// before AND after each grid.sync, plus agent-scope atomics for cursor.
__global__ __launch_bounds__(256, 4) void mono(const float* __restrict__ feat,
                                               const float* __restrict__ W,
                                               unsigned short* __restrict__ hb,
                                               const int* __restrict__ src,
                                               const int* __restrict__ dst,
                                               int* __restrict__ cursor,
                                               int* __restrict__ binned,
                                               const float* __restrict__ bias,
                                               float4* __restrict__ out4) {
    // LDS overlay: p2 hist (6252B) | transform rowLds (4096B) | gather (5632B)
    __shared__ __align__(16) char smem[NBKT * 4 + 16];
    __shared__ int claimS;
    const int t = threadIdx.x;

    // ---- phase 0: zero per-bucket counts + 2 work counters (coherent) ----
    for (int i = blockIdx.x * 256 + t; i < NBKT + 2; i += GRID * 256)
        __hip_atomic_store(&cursor[i], 0, __ATOMIC_RELAXED, __HIP_MEMORY_SCOPE_AGENT);
    __threadfence();                 // release: publish to coherent point
    cg::this_grid().sync();
    __threadfence();                 // acquire: drop stale lines (prev iteration!)

    // ---- phase 1a: p2 scatter on blocks [0, NPB) ----
    if (blockIdx.x < NPB) {
        int* hist = (int*)smem;
        for (int i = t; i < NBKT; i += 256) hist[i] = 0;
        __syncthreads();

        const int4* __restrict__ src4 = (const int4*)src;
        const int4* __restrict__ dst4 = (const int4*)dst;
        const int qlo = blockIdx.x * (EPB / 4);
        const int nq  = NE / 4;          // 400000, exact

        int4 dv[8];
        int  rk[8][4];
#pragma unroll
        for (int it = 0; it < 8; ++it) {
            const int idx = qlo + it * 256 + t;
            dv[it] = (idx < nq) ? dst4[idx] : make_int4(-1, -1, -1, -1);
        }
#pragma unroll
        for (int it = 0; it < 8; ++it)
#pragma unroll
            for (int k = 0; k < 4; ++k) {
                const int d = cmp4(dv[it], k);
                if (d >= 0) rk[it][k] = atomicAdd(&hist[d >> BKT_SHIFT], 1);
            }
        __syncthreads();

        for (int i = t; i < NBKT; i += 256) {
            const int c = hist[i];
            int base = i * BINCAP;
            if (c) base += atomicAdd(&cursor[i], c);
            hist[i] = base;
        }
        __syncthreads();

#pragma unroll
        for (int it = 0; it < 8; ++it) {
            const int idx = qlo + it * 256 + t;
            if (idx < nq) {
                const int4 s4 = src4[idx];
#pragma unroll
                for (int k = 0; k < 4; ++k) {
                    const int d = cmp4(dv[it], k);
                    const int s = cmp4(s4, k);
                    binned[hist[d >> BKT_SHIFT] + rk[it][k]] =
                        s | ((d & BKT_MASK) << 17);
                }
            }
        }
    }

    // ---- phase 1b: transform h = bf16(feat @ W^T), work-stealing tiles ----
    {
        const int lane = t & 63;
        const int wv   = t >> 6;
        float4 wreg[16];
        const float4* __restrict__ W4 = (const float4*)W;
#pragma unroll
        for (int i = 0; i < 16; ++i) wreg[i] = W4[lane * 16 + i];
        float4* rowLds = (float4*)smem;          // [TROWS][16]
        int* tilectr = cursor + NBKT;

        for (;;) {
            __syncthreads();                     // LDS overlay + claimS reuse safe
            if (t == 0) claimS = atomicAdd(tilectr, 1);
            __syncthreads();
            const int c = claimS;
            if (c >= NCHUNKT) break;
            const int tend = min(NTILE, (c + 1) * TCHUNK);
            for (int tile = c * TCHUNK; tile < tend; ++tile) {
                const int rowBase = tile * TROWS;
                rowLds[(t >> 4) * 16 + (t & 15)] =
                    ((const float4*)(feat + (size_t)(rowBase + (t >> 4)) * D))[t & 15];
                __syncthreads();
                float a0 = 0.f, a1 = 0.f, a2 = 0.f, a3 = 0.f;
#pragma unroll
                for (int k4 = 0; k4 < 16; ++k4) {
                    const float4 w  = wreg[k4];
                    const float4 r0 = rowLds[(wv * 4 + 0) * 16 + k4];
                    const float4 r1 = rowLds[(wv * 4 + 1) * 16 + k4];
                    const float4 r2 = rowLds[(wv * 4 + 2) * 16 + k4];
                    const float4 r3 = rowLds[(wv * 4 + 3) * 16 + k4];
                    a0 += r0.x * w.x + r0.y * w.y + r0.z * w.z + r0.w * w.w;
                    a1 += r1.x * w.x + r1.y * w.y + r1.z * w.z + r1.w * w.w;
                    a2 += r2.x * w.x + r2.y * w.y + r2.z * w.z + r2.w * w.w;
                    a3 += r3.x * w.x + r3.y * w.y + r3.z * w.z + r3.w * w.w;
                }
                const size_t ob = (size_t)(rowBase + wv * 4) * D + lane;
                hb[ob]         = f2bf(a0);
                hb[ob + D]     = f2bf(a1);
                hb[ob + 2 * D] = f2bf(a2);
                hb[ob + 3 * D] = f2bf(a3);
                __syncthreads();
            }
        }
    }

    __threadfence();                 // release: hb + binned + cursor counts
    cg::this_grid().sync();
    __threadfence();                 // acquire: invalidate stale hb/binned/cursor

    // ---- phase 2: gather, work-stealing buckets ----
    {
        const uint2* __restrict__ hb2 = (const uint2*)hb;
        int* cnt   = (int*)smem;             // 64
        int* pre   = cnt + BKT_NODES;        // 64
        int* sEdge = pre + BKT_NODES;        // BINCAP
        int* bktctr = cursor + NBKT + 1;
        const int q  = t >> 4;
        const int c4 = t & 15;
        const float4 bv = ((const float4*)bias)[c4];

        for (;;) {
            __syncthreads();                 // protect sEdge/claimS reuse
            if (t == 0) claimS = atomicAdd(bktctr, 1);
            __syncthreads();
            const int b = claimS;
            if (b >= NBKT) break;

            if (t < BKT_NODES) cnt[t] = 0;
            __syncthreads();

            const int gbase = b * BINCAP;
            int sz = __hip_atomic_load(&cursor[b], __ATOMIC_RELAXED,
                                       __HIP_MEMORY_SCOPE_AGENT);
            if (sz > BINCAP) sz = BINCAP;    // guard

            int pk[5], dd[5], rr[5];         // BINCAP/256 == 5
#pragma unroll
            for (int it = 0; it < 5; ++it) {
                const int e = it * 256 + t;
                if (e < sz) {
                    const int p = binned[gbase + e];
                    dd[it] = (p >> 17) & BKT_MASK;
                    pk[it] = p & SRC_MASK;
                    rr[it] = atomicAdd(&cnt[dd[it]], 1);
                } else dd[it] = -1;
            }
            __syncthreads();

            if (t < 64) {                    // scan inside wave 0
                int v = cnt[t];
#pragma unroll
                for (int s = 1; s < 64; s <<= 1) {
                    const int u = __shfl_up(v, s);
                    if (t >= s) v += u;
                }
                pre[t] = v;
            }
            __syncthreads();

#pragma unroll
            for (int it = 0; it < 5; ++it) {
                if (dd[it] >= 0)
                    sEdge[pre[dd[it]] - cnt[dd[it]] + rr[it]] = pk[it];
            }
            __syncthreads();

#pragma unroll
            for (int i = 0; i < 4; ++i) {
                const int n    = q * 4 + i;
                const int node = b * BKT_NODES + n;
                if (node >= NN) break;       // uniform within quarter
                const int end = pre[n];
                float ax = 0.f, ay = 0.f, az = 0.f, aw = 0.f;
                for (int e = end - cnt[n]; e < end; e += 8) {
                    uint2 x[8];
#pragma unroll
                    for (int j = 0; j < 8; ++j) {
                        const int idx = (e + j < end) ? sEdge[e + j] : -1;
                        x[j] = (idx >= 0) ? hb2[(size_t)idx * 16 + c4]
                                          : make_uint2(0u, 0u);
                    }
#pragma unroll
                    for (int j = 0; j < 8; ++j) {
                        ax += __uint_as_float(x[j].x << 16);
                        ay += __uint_as_float(x[j].x & 0xFFFF0000u);
                        az += __uint_as_float(x[j].y << 16);
                        aw += __uint_as_float(x[j].y & 0xFFFF0000u);
                    }
                }
                float4 v;
                v.x = ax + bv.x; v.y = ay + bv.y; v.z = az + bv.z; v.w = aw + bv.w;
                out4[(size_t)node * 16 + c4] = v;
            }
        }
    }
}

// ======================= fallback path (round-4 validated) =================
__global__ __launch_bounds__(256) void seed_cursor(int* __restrict__ cursor) {
    const int i = blockIdx.x * 256 + threadIdx.x;
    if (i < NBKT) cursor[i] = 0;
}

__global__ __launch_bounds__(256) void fused_tp2(const float* __restrict__ feat,
                                                 const float* __restrict__ W,
                                                 unsigned short* __restrict__ hb,
                                                 const int* __restrict__ src,
                                                 const int* __restrict__ dst,
                                                 int* __restrict__ cursor,
                                                 int* __restrict__ binned) {
    __shared__ int hist[NBKT];
    __shared__ float4 rowLds[TROWS][16];

    if (blockIdx.x < NPB) {
        for (int i = threadIdx.x; i < NBKT; i += 256) hist[i] = 0;
        __syncthreads();
        const int4* __restrict__ src4 = (const int4*)src;
        const int4* __restrict__ dst4 = (const int4*)dst;
        const int qlo = blockIdx.x * (EPB / 4);
        const int nq  = NE / 4;
        int4 dv[8];
        int  rk[8][4];
#pragma unroll
        for (int it = 0; it < 8; ++it) {
            const int idx = qlo + it * 256 + threadIdx.x;
            dv[it] = (idx < nq) ? dst4[idx] : make_int4(-1, -1, -1, -1);
        }
#pragma unroll
        for (int it = 0; it < 8; ++it)
#pragma unroll
            for (int k = 0; k < 4; ++k) {
                const int d = cmp4(dv[it], k);
                if (d >= 0) rk[it][k] = atomicAdd(&hist[d >> BKT_SHIFT], 1);
            }
        __syncthreads();
        for (int i = threadIdx.x; i < NBKT; i += 256) {
            const int c = hist[i];
            int base = i * BINCAP;
            if (c) base += atomicAdd(&cursor[i], c);
            hist[i] = base;
        }
        __syncthreads();
#pragma unroll
        for (int it = 0; it < 8; ++it) {
            const int idx = qlo + it * 256 + threadIdx.x;
            if (idx < nq) {
                const int4 s4 = src4[idx];
#pragma unroll
                for (int k = 0; k < 4; ++k) {
                    const int d = cmp4(dv[it], k);
                    const int s = cmp4(s4, k);
                    binned[hist[d >> BKT_SHIFT] + rk[it][k]] =
                        s | ((d & BKT_MASK) << 17);
                }
            }
        }
    } else {
        const int bid  = blockIdx.x - NPB;
        const int lane = threadIdx.x & 63;
        const int wv   = threadIdx.x >> 6;
        float4 wreg[16];
        const float4* __restrict__ W4 = (const float4*)W;
#pragma unroll
        for (int i = 0; i < 16; ++i) wreg[i] = W4[lane * 16 + i];
        for (int tile = bid; tile < NTILE; tile += TGRID) {
            const int rowBase = tile * TROWS;
            rowLds[threadIdx.x >> 4][threadIdx.x & 15] =
                ((const float4*)(feat + (size_t)(rowBase + (threadIdx.x >> 4)) * D))[threadIdx.x & 15];
            __syncthreads();
            float a0 = 0.f, a1 = 0.f, a2 = 0.f, a3 = 0.f;
#pragma unroll
            for (int k4 = 0; k4 < 16; ++k4) {
                const float4 w  = wreg[k4];
                const float4 r0 = rowLds[wv * 4 + 0][k4];
                const float4 r1 = rowLds[wv * 4 + 1][k4];
                const float4 r2 = rowLds[wv * 4 + 2][k4];
                const float4 r3 = rowLds[wv * 4 + 3][k4];
                a0 += r0.x * w.x + r0.y * w.y + r0.z * w.z + r0.w * w.w;
                a1 += r1.x * w.x + r1.y * w.y + r1.z * w.z + r1.w * w.w;
                a2 += r2.x * w.x + r2.y * w.y + r2.z * w.z + r2.w * w.w;
                a3 += r3.x * w.x + r3.y * w.y + r3.z * w.z + r3.w * w.w;
            }
            const size_t ob = (size_t)(rowBase + wv * 4) * D + lane;
            hb[ob]         = f2bf(a0);
            hb[ob + D]     = f2bf(a1);
            hb[ob + 2 * D] = f2bf(a2);
            hb[ob + 3 * D] = f2bf(a3);
            __syncthreads();
        }
    }
}

__global__ __launch_bounds__(256) void bucket_gather(const uint2* __restrict__ hb2,
                                                     const int* __restrict__ binned,
                                                     const int* __restrict__ cursor,
                                                     const float* __restrict__ bias,
                                                     float4* __restrict__ out4) {
    __shared__ int cnt[BKT_NODES];
    __shared__ int pre[BKT_NODES];
    __shared__ int sEdge[BINCAP];
    const int t = threadIdx.x;
    const int b = blockIdx.x;
    if (t < BKT_NODES) cnt[t] = 0;
    __syncthreads();

    const int gbase = b * BINCAP;
    int sz = cursor[b];
    if (sz > BINCAP) sz = BINCAP;

    int pk[5], dd[5], rr[5];
#pragma unroll
    for (int it = 0; it < 5; ++it) {
        const int e = it * 256 + t;
        if (e < sz) {
            const int p = binned[gbase + e];
            dd[it] = (p >> 17) & BKT_MASK;
            pk[it] = p & SRC_MASK;
            rr[it] = atomicAdd(&cnt[dd[it]], 1);
        } else dd[it] = -1;
    }
    __syncthreads();

    if (t < 64) {
        int v = cnt[t];
#pragma unroll
        for (int s = 1; s < 64; s <<= 1) {
            const int u = __shfl_up(v, s);
            if (t >= s) v += u;
        }
        pre[t] = v;
    }
    __syncthreads();

#pragma unroll
    for (int it = 0; it < 5; ++it) {
        if (dd[it] >= 0)
            sEdge[pre[dd[it]] - cnt[dd[it]] + rr[it]] = pk[it];
    }
    __syncthreads();

    const int q  = t >> 4;
    const int c4 = t & 15;
    const float4 bv = ((const float4*)bias)[c4];
#pragma unroll
    for (int i = 0; i < 4; ++i) {
        const int n    = q * 4 + i;
        const int node = b * BKT_NODES + n;
        if (node >= NN) break;
        const int end = pre[n];
        float ax = 0.f, ay = 0.f, az = 0.f, aw = 0.f;
        for (int e = end - cnt[n]; e < end; e += 8) {
            uint2 x[8];
#pragma unroll
            for (int j = 0; j < 8; ++j) {
                const int idx = (e + j < end) ? sEdge[e + j] : -1;
                x[j] = (idx >= 0) ? hb2[(size_t)idx * 16 + c4] : make_uint2(0u, 0u);
            }
#pragma unroll
            for (int j = 0; j < 8; ++j) {
                ax += __uint_as_float(x[j].x << 16);
                ay += __uint_as_float(x[j].x & 0xFFFF0000u);
                az += __uint_as_float(x[j].y << 16);
                aw += __uint_as_float(x[j].y & 0xFFFF0000u);
            }
        }
        float4 v;
        v.x = ax + bv.x; v.y = ay + bv.y; v.z = az + bv.z; v.w = aw + bv.w;
        out4[(size_t)node * 16 + c4] = v;
    }
}

extern "C" void kernel_launch(void* const* d_in, const int* in_sizes, int n_in,
                              void* d_out, int out_size, void* d_ws, size_t ws_size,
                              hipStream_t stream) {
    const float* feat = (const float*)d_in[0];
    const int*   src  = (const int*)d_in[1];
    const int*   dst  = (const int*)d_in[2];
    const float* W    = (const float*)d_in[3];
    const float* bias = (const float*)d_in[4];
    float4* out = (float4*)d_out;

    unsigned short* hb = (unsigned short*)d_ws;       // NN*D bf16 (12.8 MB)
    int* binned = (int*)(hb + (size_t)NN * D);        // NBKT*BINCAP (8.0 MB)
    int* cursor = binned + NBKT * BINCAP;             // NBKT counts + 2 work ctrs

    void* args[] = { (void*)&feat, (void*)&W, (void*)&hb, (void*)&src, (void*)&dst,
                     (void*)&cursor, (void*)&binned, (void*)&bias, (void*)&out };
    hipError_t err = hipLaunchCooperativeKernel((void*)mono, dim3(GRID), dim3(256),
                                                args, 0, stream);
    if (err != hipSuccess) {
        (void)hipGetLastError();   // clear sticky error, take validated 3-launch path
        seed_cursor<<<(NBKT + 255) / 256, 256, 0, stream>>>(cursor);
        fused_tp2<<<NPB + TGRID, 256, 0, stream>>>(feat, W, hb, src, dst, cursor, binned);
        bucket_gather<<<NBKT, 256, 0, stream>>>((const uint2*)hb, binned, cursor,
                                                bias, out);
    }
}

// Round 8
// 176.287 us; speedup vs baseline: 4.0841x; 4.0841x over previous
//
#include <hip/hip_runtime.h>

#define NN 100000
#define NE 1600000
#define D 64
#define BKT_SHIFT 6
#define BKT_NODES 64
#define BKT_MASK 63
#define NBKT 1563           // ceil(NN / 64) buckets of 64 nodes
#define SRC_MASK 0x1FFFF    // src < 100000 < 2^17
#define EPB 4096            // edges per p2 block (391 blocks, 16 edges/thread)
#define NPB ((NE + EPB - 1) / EPB)   // 391
#define BINCAP 1280         // mean 1024, sd ~32 -> 8 sigma
#define TROWS 16            // rows per transform tile
#define NTILE (NN / TROWS)  // 6250 exact
#define TCHUNK 4            // tiles per transform work-claim
#define NCHUNKT ((NTILE + TCHUNK - 1) / TCHUNK)  // 1563
#define TGRID 2048          // dedicated transform blocks

// float -> bf16 (round-to-nearest-even; inputs finite)
__device__ __forceinline__ unsigned short f2bf(float f) {
    unsigned u = __float_as_uint(f);
    unsigned r = u + 0x7FFF + ((u >> 16) & 1);
    return (unsigned short)(r >> 16);
}

__device__ __forceinline__ int cmp4(const int4& v, int k) {
    return k == 0 ? v.x : k == 1 ? v.y : k == 2 ? v.z : v.w;
}

// ---------------- seed: zero per-bucket counts + transform tile counter ----
__global__ __launch_bounds__(256) void seed_cursor(int* __restrict__ cursor) {
    const int i = blockIdx.x * 256 + threadIdx.x;
    if (i < NBKT + 1) cursor[i] = 0;
}

// ---------------- fused: p2 (blocks < NPB) then ALL blocks steal transform -
// Round-4 structure, rebalanced: p2's tail was 196 blocks on 256 CUs (<1
// block/CU after transform retired) and set fused's 49.5us duration.  Now
// 391 p2 blocks with half the per-block work, and p2 blocks fall through
// into transform work-stealing (claim loop validated on HW by round-7 mono).
__global__ __launch_bounds__(256) void fused_tp2(const float* __restrict__ feat,
                                                 const float* __restrict__ W,
                                                 unsigned short* __restrict__ hb,
                                                 const int* __restrict__ src,
                                                 const int* __restrict__ dst,
                                                 int* __restrict__ cursor,
                                                 int* __restrict__ binned) {
    __shared__ int hist[NBKT];           // p2: rank counters, then bases
    __shared__ float4 rowLds[TROWS][16]; // transform: staged rows
    __shared__ int claimS;
    const int t = threadIdx.x;

    if (blockIdx.x < NPB) {
        // ---------------- p2: 4096 edges, 16/thread ----------------
        for (int i = t; i < NBKT; i += 256) hist[i] = 0;
        __syncthreads();

        const int4* __restrict__ src4 = (const int4*)src;
        const int4* __restrict__ dst4 = (const int4*)dst;
        const int qlo = blockIdx.x * (EPB / 4);
        const int nq  = NE / 4;          // 400000, exact

        int4 dv[4];
        int  rk[4][4];
#pragma unroll
        for (int it = 0; it < 4; ++it) {
            const int idx = qlo + it * 256 + t;
            dv[it] = (idx < nq) ? dst4[idx] : make_int4(-1, -1, -1, -1);
        }
#pragma unroll
        for (int it = 0; it < 4; ++it)
#pragma unroll
            for (int k = 0; k < 4; ++k) {
                const int d = cmp4(dv[it], k);
                if (d >= 0) rk[it][k] = atomicAdd(&hist[d >> BKT_SHIFT], 1);
            }
        __syncthreads();

        // reserve global ranges; hist becomes base (packed cursors: hot L2
        // lines — padding them was a measured regression, round 1)
        for (int i = t; i < NBKT; i += 256) {
            const int c = hist[i];
            int base = i * BINCAP;
            if (c) base += atomicAdd(&cursor[i], c);
            hist[i] = base;
        }
        __syncthreads();

#pragma unroll
        for (int it = 0; it < 4; ++it) {
            const int idx = qlo + it * 256 + t;
            if (idx < nq) {
                const int4 s4 = src4[idx];
#pragma unroll
                for (int k = 0; k < 4; ++k) {
                    const int d = cmp4(dv[it], k);
                    const int s = cmp4(s4, k);
                    binned[hist[d >> BKT_SHIFT] + rk[it][k]] =
                        s | ((d & BKT_MASK) << 17);
                }
            }
        }
    }

    // ---------------- transform: h = bf16(feat @ W^T), work-stealing -------
    {
        const int lane = t & 63;
        const int wv   = t >> 6;
        float4 wreg[16];
        const float4* __restrict__ W4 = (const float4*)W;
#pragma unroll
        for (int i = 0; i < 16; ++i) wreg[i] = W4[lane * 16 + i];
        int* tilectr = cursor + NBKT;

        for (;;) {
            __syncthreads();                     // LDS/claimS reuse safe
            if (t == 0) claimS = atomicAdd(tilectr, 1);
            __syncthreads();
            const int c = claimS;
            if (c >= NCHUNKT) break;
            const int tend = min(NTILE, (c + 1) * TCHUNK);
            for (int tile = c * TCHUNK; tile < tend; ++tile) {
                const int rowBase = tile * TROWS;
                rowLds[t >> 4][t & 15] =
                    ((const float4*)(feat + (size_t)(rowBase + (t >> 4)) * D))[t & 15];
                __syncthreads();
                float a0 = 0.f, a1 = 0.f, a2 = 0.f, a3 = 0.f;
#pragma unroll
                for (int k4 = 0; k4 < 16; ++k4) {
                    const float4 w  = wreg[k4];
                    const float4 r0 = rowLds[wv * 4 + 0][k4];
                    const float4 r1 = rowLds[wv * 4 + 1][k4];
                    const float4 r2 = rowLds[wv * 4 + 2][k4];
                    const float4 r3 = rowLds[wv * 4 + 3][k4];
                    a0 += r0.x * w.x + r0.y * w.y + r0.z * w.z + r0.w * w.w;
                    a1 += r1.x * w.x + r1.y * w.y + r1.z * w.z + r1.w * w.w;
                    a2 += r2.x * w.x + r2.y * w.y + r2.z * w.z + r2.w * w.w;
                    a3 += r3.x * w.x + r3.y * w.y + r3.z * w.z + r3.w * w.w;
                }
                const size_t ob = (size_t)(rowBase + wv * 4) * D + lane;
                hb[ob]         = f2bf(a0);
                hb[ob + D]     = f2bf(a1);
                hb[ob + 2 * D] = f2bf(a2);
                hb[ob + 3 * D] = f2bf(a3);
                __syncthreads();
            }
        }
    }
}

// ---------------- bucket_gather: round-4 validated body --------------------
__global__ __launch_bounds__(256) void bucket_gather(const uint2* __restrict__ hb2,
                                                     const int* __restrict__ binned,
                                                     const int* __restrict__ cursor,
                                                     const float* __restrict__ bias,
                                                     float4* __restrict__ out4) {
    __shared__ int cnt[BKT_NODES];
    __shared__ int pre[BKT_NODES];
    __shared__ int sEdge[BINCAP];
    const int t = threadIdx.x;
    const int b = blockIdx.x;
    if (t < BKT_NODES) cnt[t] = 0;
    __syncthreads();

    const int gbase = b * BINCAP;
    int sz = cursor[b];
    if (sz > BINCAP) sz = BINCAP;    // guard

    int pk[5], dd[5], rr[5];         // BINCAP/256 == 5
#pragma unroll
    for (int it = 0; it < 5; ++it) {
        const int e = it * 256 + t;
        if (e < sz) {
            const int p = binned[gbase + e];
            dd[it] = (p >> 17) & BKT_MASK;
            pk[it] = p & SRC_MASK;
            rr[it] = atomicAdd(&cnt[dd[it]], 1);
        } else dd[it] = -1;
    }
    __syncthreads();

    // inclusive scan of cnt[64] inside wave 0
    if (t < 64) {
        int v = cnt[t];
#pragma unroll
        for (int s = 1; s < 64; s <<= 1) {
            const int u = __shfl_up(v, s);
            if (t >= s) v += u;
        }
        pre[t] = v;
    }
    __syncthreads();

#pragma unroll
    for (int it = 0; it < 5; ++it) {
        if (dd[it] >= 0)
            sEdge[pre[dd[it]] - cnt[dd[it]] + rr[it]] = pk[it];
    }
    __syncthreads();

    const int q  = t >> 4;           // quarter q owns nodes q*4..q*4+3
    const int c4 = t & 15;           // 8-byte column group (4 bf16 cols)
    const float4 bv = ((const float4*)bias)[c4];
#pragma unroll
    for (int i = 0; i < 4; ++i) {
        const int n    = q * 4 + i;
        const int node = b * BKT_NODES + n;
        if (node >= NN) break;       // uniform within quarter
        const int end = pre[n];
        float ax = 0.f, ay = 0.f, az = 0.f, aw = 0.f;
        for (int e = end - cnt[n]; e < end; e += 8) {
            uint2 x[8];
#pragma unroll
            for (int j = 0; j < 8; ++j) {
                const int idx = (e + j < end) ? sEdge[e + j] : -1;
                x[j] = (idx >= 0) ? hb2[(size_t)idx * 16 + c4] : make_uint2(0u, 0u);
            }
#pragma unroll
            for (int j = 0; j < 8; ++j) {
                ax += __uint_as_float(x[j].x << 16);
                ay += __uint_as_float(x[j].x & 0xFFFF0000u);
                az += __uint_as_float(x[j].y << 16);
                aw += __uint_as_float(x[j].y & 0xFFFF0000u);
            }
        }
        float4 v;
        v.x = ax + bv.x; v.y = ay + bv.y; v.z = az + bv.z; v.w = aw + bv.w;
        out4[(size_t)node * 16 + c4] = v;
    }
}

extern "C" void kernel_launch(void* const* d_in, const int* in_sizes, int n_in,
                              void* d_out, int out_size, void* d_ws, size_t ws_size,
                              hipStream_t stream) {
    const float* feat = (const float*)d_in[0];
    const int*   src  = (const int*)d_in[1];
    const int*   dst  = (const int*)d_in[2];
    const float* W    = (const float*)d_in[3];
    const float* bias = (const float*)d_in[4];
    float4* out = (float4*)d_out;

    // workspace layout (~20.8 MB)
    unsigned short* hb = (unsigned short*)d_ws;       // NN*D bf16 (12.8 MB)
    int* binned = (int*)(hb + (size_t)NN * D);        // NBKT*BINCAP (8.0 MB)
    int* cursor = binned + NBKT * BINCAP;             // NBKT counts + tile ctr

    seed_cursor<<<(NBKT + 256) / 256, 256, 0, stream>>>(cursor);
    fused_tp2<<<NPB + TGRID, 256, 0, stream>>>(feat, W, hb, src, dst, cursor, binned);
    bucket_gather<<<NBKT, 256, 0, stream>>>((const uint2*)hb, binned, cursor,
                                            bias, out);
}

// Round 9
// 160.361 us; speedup vs baseline: 4.4897x; 1.0993x over previous
//
#include <hip/hip_runtime.h>

#define NN 100000
#define NE 1600000
#define D 64
#define BKT_SHIFT 7
#define BKT_NODES 128
#define BKT_MASK 127
#define NBKT 782            // ceil(NN / 128) buckets of 128 nodes
#define SRC_MASK 0x1FFFF    // src < 100000 < 2^17
#define EPB 8192            // edges per p2 block (196 blocks, 32 edges/thread)
#define NPB ((NE + EPB - 1) / EPB)   // 196
#define BINCAP 2560         // mean 2048, sd ~45 -> 11 sigma
#define TROWS 16            // rows per transform tile
#define NTILE (NN / TROWS)  // 6250 exact
#define TGRID 2048          // dedicated transform blocks

// float -> bf16 (round-to-nearest-even; inputs finite)
__device__ __forceinline__ unsigned short f2bf(float f) {
    unsigned u = __float_as_uint(f);
    unsigned r = u + 0x7FFF + ((u >> 16) & 1);
    return (unsigned short)(r >> 16);
}

__device__ __forceinline__ int cmp4(const int4& v, int k) {
    return k == 0 ? v.x : k == 1 ? v.y : k == 2 ? v.z : v.w;
}

// ---------------- seed: zero per-bucket counts -----------------------------
__global__ __launch_bounds__(256) void seed_cursor(int* __restrict__ cursor) {
    const int i = blockIdx.x * 256 + threadIdx.x;
    if (i < NBKT) cursor[i] = 0;
}

// ---------------- fused: p2 scatter (blocks < NPB) + transform (rest) ------
// Round-4 structure (196 p2 blocks, static transform — work-steal and
// EPB=4096 both measured as regressions in round 8).  NBKT halved to 782:
// p2's cost is NPB x NBKT fixed overhead (hist zero/scan + cursor atomics),
// so 128-node buckets halve it; run length per (block,bucket) doubles to
// ~10.5 edges (42 B) cutting write-allocate amplification.
__global__ __launch_bounds__(256) void fused_tp2(const float* __restrict__ feat,
                                                 const float* __restrict__ W,
                                                 unsigned short* __restrict__ hb,
                                                 const int* __restrict__ src,
                                                 const int* __restrict__ dst,
                                                 int* __restrict__ cursor,
                                                 int* __restrict__ binned) {
    __shared__ int hist[NBKT];           // p2: rank counters, then bases
    __shared__ float4 rowLds[TROWS][16]; // transform: staged rows
    const int t = threadIdx.x;

    if (blockIdx.x < NPB) {
        // ---------------- p2: 8192 edges, 32/thread ----------------
        for (int i = t; i < NBKT; i += 256) hist[i] = 0;
        __syncthreads();

        const int4* __restrict__ src4 = (const int4*)src;
        const int4* __restrict__ dst4 = (const int4*)dst;
        const int qlo = blockIdx.x * (EPB / 4);
        const int nq  = NE / 4;          // 400000, exact

        int4 dv[8];
        int  rk[8][4];
#pragma unroll
        for (int it = 0; it < 8; ++it) {
            const int idx = qlo + it * 256 + t;
            dv[it] = (idx < nq) ? dst4[idx] : make_int4(-1, -1, -1, -1);
        }
#pragma unroll
        for (int it = 0; it < 8; ++it)
#pragma unroll
            for (int k = 0; k < 4; ++k) {
                const int d = cmp4(dv[it], k);
                if (d >= 0) rk[it][k] = atomicAdd(&hist[d >> BKT_SHIFT], 1);
            }
        __syncthreads();

        // reserve global ranges; hist becomes base (packed cursors: hot L2
        // lines — padding them was a measured regression, round 1)
        for (int i = t; i < NBKT; i += 256) {
            const int c = hist[i];
            int base = i * BINCAP;
            if (c) base += atomicAdd(&cursor[i], c);
            hist[i] = base;
        }
        __syncthreads();

#pragma unroll
        for (int it = 0; it < 8; ++it) {
            const int idx = qlo + it * 256 + t;
            if (idx < nq) {
                const int4 s4 = src4[idx];
#pragma unroll
                for (int k = 0; k < 4; ++k) {
                    const int d = cmp4(dv[it], k);
                    const int s = cmp4(s4, k);
                    binned[hist[d >> BKT_SHIFT] + rk[it][k]] =
                        s | ((d & BKT_MASK) << 17);
                }
            }
        }
    } else {
        // ---------------- transform: h = bf16(feat @ W^T), static ----------
        const int bid  = blockIdx.x - NPB;
        const int lane = t & 63;
        const int wv   = t >> 6;
        float4 wreg[16];
        const float4* __restrict__ W4 = (const float4*)W;
#pragma unroll
        for (int i = 0; i < 16; ++i) wreg[i] = W4[lane * 16 + i];

        for (int tile = bid; tile < NTILE; tile += TGRID) {
            const int rowBase = tile * TROWS;
            rowLds[t >> 4][t & 15] =
                ((const float4*)(feat + (size_t)(rowBase + (t >> 4)) * D))[t & 15];
            __syncthreads();
            float a0 = 0.f, a1 = 0.f, a2 = 0.f, a3 = 0.f;
#pragma unroll
            for (int k4 = 0; k4 < 16; ++k4) {
                const float4 w  = wreg[k4];
                const float4 r0 = rowLds[wv * 4 + 0][k4];
                const float4 r1 = rowLds[wv * 4 + 1][k4];
                const float4 r2 = rowLds[wv * 4 + 2][k4];
                const float4 r3 = rowLds[wv * 4 + 3][k4];
                a0 += r0.x * w.x + r0.y * w.y + r0.z * w.z + r0.w * w.w;
                a1 += r1.x * w.x + r1.y * w.y + r1.z * w.z + r1.w * w.w;
                a2 += r2.x * w.x + r2.y * w.y + r2.z * w.z + r2.w * w.w;
                a3 += r3.x * w.x + r3.y * w.y + r3.z * w.z + r3.w * w.w;
            }
            const size_t ob = (size_t)(rowBase + wv * 4) * D + lane;
            hb[ob]         = f2bf(a0);
            hb[ob + D]     = f2bf(a1);
            hb[ob + 2 * D] = f2bf(a2);
            hb[ob + 3 * D] = f2bf(a3);
            __syncthreads();
        }
    }
}

// ---------------- bucket_gather: 128-node buckets, register accumulate -----
// 782 blocks (~3/CU; round-0-validated geometry).  Counting-sort ~2048
// edges into per-node segments (two-wave shfl scan), then quarter-wave per
// node with 8 independent 8 B gather loads in flight per lane; fp32
// register accumulate, coalesced float4 store with bias.
__global__ __launch_bounds__(256) void bucket_gather(const uint2* __restrict__ hb2,
                                                     const int* __restrict__ binned,
                                                     const int* __restrict__ cursor,
                                                     const float* __restrict__ bias,
                                                     float4* __restrict__ out4) {
    __shared__ int cnt[BKT_NODES];
    __shared__ int pre[BKT_NODES];
    __shared__ int sEdge[BINCAP];
    const int t = threadIdx.x;
    const int b = blockIdx.x;
    if (t < BKT_NODES) cnt[t] = 0;
    __syncthreads();

    const int gbase = b * BINCAP;
    int sz = cursor[b];
    if (sz > BINCAP) sz = BINCAP;    // 11-sigma guard

    // rank edges per node (counting sort pass 1)
    int pk[10], dd[10], rr[10];      // BINCAP/256 == 10
#pragma unroll
    for (int it = 0; it < 10; ++it) {
        const int e = it * 256 + t;
        if (e < sz) {
            const int p = binned[gbase + e];
            dd[it] = (p >> 17) & BKT_MASK;
            pk[it] = p & SRC_MASK;
            rr[it] = atomicAdd(&cnt[dd[it]], 1);
        } else dd[it] = -1;
    }
    __syncthreads();

    // inclusive scan of cnt[128]: per-wave shfl scan, then cross-wave fixup
    if (t < 128) {
        int v = cnt[t];
#pragma unroll
        for (int s = 1; s < 64; s <<= 1) {
            const int u = __shfl_up(v, s);
            if ((t & 63) >= s) v += u;
        }
        pre[t] = v;
    }
    __syncthreads();
    if (t >= 64 && t < 128) pre[t] += pre[63];
    __syncthreads();

    // scatter into per-node segments: node d owns [pre[d]-cnt[d], pre[d])
#pragma unroll
    for (int it = 0; it < 10; ++it) {
        if (dd[it] >= 0)
            sEdge[pre[dd[it]] - cnt[dd[it]] + rr[it]] = pk[it];
    }
    __syncthreads();

    // accumulate: quarter-wave per node, 4 fp32 cols per lane, 8 loads in flight
    const int q  = t >> 4;           // 16 quarters; quarter q owns nodes q*8..q*8+7
    const int c4 = t & 15;           // 8-byte column group (4 bf16 cols)
    const float4 bv = ((const float4*)bias)[c4];
#pragma unroll
    for (int i = 0; i < 8; ++i) {
        const int n    = q * 8 + i;
        const int node = b * BKT_NODES + n;
        if (node >= NN) break;       // uniform within quarter
        const int end = pre[n];
        float ax = 0.f, ay = 0.f, az = 0.f, aw = 0.f;
        for (int e = end - cnt[n]; e < end; e += 8) {
            uint2 x[8];
#pragma unroll
            for (int j = 0; j < 8; ++j) {
                const int idx = (e + j < end) ? sEdge[e + j] : -1;
                x[j] = (idx >= 0) ? hb2[(size_t)idx * 16 + c4] : make_uint2(0u, 0u);
            }
#pragma unroll
            for (int j = 0; j < 8; ++j) {
                ax += __uint_as_float(x[j].x << 16);
                ay += __uint_as_float(x[j].x & 0xFFFF0000u);
                az += __uint_as_float(x[j].y << 16);
                aw += __uint_as_float(x[j].y & 0xFFFF0000u);
            }
        }
        float4 v;
        v.x = ax + bv.x; v.y = ay + bv.y; v.z = az + bv.z; v.w = aw + bv.w;
        out4[(size_t)node * 16 + c4] = v;
    }
}

extern "C" void kernel_launch(void* const* d_in, const int* in_sizes, int n_in,
                              void* d_out, int out_size, void* d_ws, size_t ws_size,
                              hipStream_t stream) {
    const float* feat = (const float*)d_in[0];
    const int*   src  = (const int*)d_in[1];
    const int*   dst  = (const int*)d_in[2];
    const float* W    = (const float*)d_in[3];
    const float* bias = (const float*)d_in[4];
    float4* out = (float4*)d_out;

    // workspace layout (~20.8 MB)
    unsigned short* hb = (unsigned short*)d_ws;       // NN*D bf16 (12.8 MB)
    int* binned = (int*)(hb + (size_t)NN * D);        // NBKT*BINCAP (8.0 MB)
    int* cursor = binned + NBKT * BINCAP;             // NBKT counts

    seed_cursor<<<(NBKT + 255) / 256, 256, 0, stream>>>(cursor);
    fused_tp2<<<NPB + TGRID, 256, 0, stream>>>(feat, W, hb, src, dst, cursor, binned);
    bucket_gather<<<NBKT, 256, 0, stream>>>((const uint2*)hb, binned, cursor,
                                            bias, out);
}

// Round 10
// 156.964 us; speedup vs baseline: 4.5868x; 1.0216x over previous
//
#include <hip/hip_runtime.h>

#define NN 100000
#define NE 1600000
#define D 64
#define BKT_SHIFT 7
#define BKT_NODES 128
#define BKT_MASK 127
#define NBKT 782            // ceil(NN / 128) buckets of 128 nodes
#define SRC_MASK 0x1FFFF    // src < 100000 < 2^17
#define EPB 8192            // edges per p2 block (196 blocks, 32 edges/thread)
#define NPB ((NE + EPB - 1) / EPB)   // 196
#define BINCAP 2560         // mean 2048, sd ~45 -> 11 sigma
#define GT 512              // gather block size (4 rounds/CU -> 2 half-rounds)
#define TROWS 16            // rows per transform tile
#define NTILE (NN / TROWS)  // 6250 exact
#define TGRID 2048          // dedicated transform blocks

// float -> bf16 (round-to-nearest-even; inputs finite)
__device__ __forceinline__ unsigned short f2bf(float f) {
    unsigned u = __float_as_uint(f);
    unsigned r = u + 0x7FFF + ((u >> 16) & 1);
    return (unsigned short)(r >> 16);
}

__device__ __forceinline__ int cmp4(const int4& v, int k) {
    return k == 0 ? v.x : k == 1 ? v.y : k == 2 ? v.z : v.w;
}

// ---------------- seed: zero per-bucket counts -----------------------------
__global__ __launch_bounds__(256) void seed_cursor(int* __restrict__ cursor) {
    const int i = blockIdx.x * 256 + threadIdx.x;
    if (i < NBKT) cursor[i] = 0;
}

// ---------------- fused: p2 scatter (blocks < NPB) + transform (rest) ------
// Round-9 validated: 128-node buckets cut p2's NPB x NBKT overhead and
// write-amp (WRITE 44->34 MB measured, fused 49.5->45.8us).
__global__ __launch_bounds__(256) void fused_tp2(const float* __restrict__ feat,
                                                 const float* __restrict__ W,
                                                 unsigned short* __restrict__ hb,
                                                 const int* __restrict__ src,
                                                 const int* __restrict__ dst,
                                                 int* __restrict__ cursor,
                                                 int* __restrict__ binned) {
    __shared__ int hist[NBKT];           // p2: rank counters, then bases
    __shared__ float4 rowLds[TROWS][16]; // transform: staged rows
    const int t = threadIdx.x;

    if (blockIdx.x < NPB) {
        // ---------------- p2: 8192 edges, 32/thread ----------------
        for (int i = t; i < NBKT; i += 256) hist[i] = 0;
        __syncthreads();

        const int4* __restrict__ src4 = (const int4*)src;
        const int4* __restrict__ dst4 = (const int4*)dst;
        const int qlo = blockIdx.x * (EPB / 4);
        const int nq  = NE / 4;          // 400000, exact

        int4 dv[8];
        int  rk[8][4];
#pragma unroll
        for (int it = 0; it < 8; ++it) {
            const int idx = qlo + it * 256 + t;
            dv[it] = (idx < nq) ? dst4[idx] : make_int4(-1, -1, -1, -1);
        }
#pragma unroll
        for (int it = 0; it < 8; ++it)
#pragma unroll
            for (int k = 0; k < 4; ++k) {
                const int d = cmp4(dv[it], k);
                if (d >= 0) rk[it][k] = atomicAdd(&hist[d >> BKT_SHIFT], 1);
            }
        __syncthreads();

        // reserve global ranges; hist becomes base (packed cursors: hot L2
        // lines — padding them was a measured regression, round 1)
        for (int i = t; i < NBKT; i += 256) {
            const int c = hist[i];
            int base = i * BINCAP;
            if (c) base += atomicAdd(&cursor[i], c);
            hist[i] = base;
        }
        __syncthreads();

#pragma unroll
        for (int it = 0; it < 8; ++it) {
            const int idx = qlo + it * 256 + t;
            if (idx < nq) {
                const int4 s4 = src4[idx];
#pragma unroll
                for (int k = 0; k < 4; ++k) {
                    const int d = cmp4(dv[it], k);
                    const int s = cmp4(s4, k);
                    binned[hist[d >> BKT_SHIFT] + rk[it][k]] =
                        s | ((d & BKT_MASK) << 17);
                }
            }
        }
    } else {
        // ---------------- transform: h = bf16(feat @ W^T), static ----------
        const int bid  = blockIdx.x - NPB;
        const int lane = t & 63;
        const int wv   = t >> 6;
        float4 wreg[16];
        const float4* __restrict__ W4 = (const float4*)W;
#pragma unroll
        for (int i = 0; i < 16; ++i) wreg[i] = W4[lane * 16 + i];

        for (int tile = bid; tile < NTILE; tile += TGRID) {
            const int rowBase = tile * TROWS;
            rowLds[t >> 4][t & 15] =
                ((const float4*)(feat + (size_t)(rowBase + (t >> 4)) * D))[t & 15];
            __syncthreads();
            float a0 = 0.f, a1 = 0.f, a2 = 0.f, a3 = 0.f;
#pragma unroll
            for (int k4 = 0; k4 < 16; ++k4) {
                const float4 w  = wreg[k4];
                const float4 r0 = rowLds[wv * 4 + 0][k4];
                const float4 r1 = rowLds[wv * 4 + 1][k4];
                const float4 r2 = rowLds[wv * 4 + 2][k4];
                const float4 r3 = rowLds[wv * 4 + 3][k4];
                a0 += r0.x * w.x + r0.y * w.y + r0.z * w.z + r0.w * w.w;
                a1 += r1.x * w.x + r1.y * w.y + r1.z * w.z + r1.w * w.w;
                a2 += r2.x * w.x + r2.y * w.y + r2.z * w.z + r2.w * w.w;
                a3 += r3.x * w.x + r3.y * w.y + r3.z * w.z + r3.w * w.w;
            }
            const size_t ob = (size_t)(rowBase + wv * 4) * D + lane;
            hb[ob]         = f2bf(a0);
            hb[ob + D]     = f2bf(a1);
            hb[ob + 2 * D] = f2bf(a2);
            hb[ob + 3 * D] = f2bf(a3);
            __syncthreads();
        }
    }
}

// ---------------- bucket_gather: 128-node buckets, 512 threads -------------
// Round-9 regression diagnosis: 782 blocks x 256 thr = 3.05 blocks/CU ->
// wall time quantizes to 4 full per-block rounds with only 12 waves/CU in
// flight.  512 threads halve the per-block round (4 edges/thread sort, 32
// quarter-waves x 4 nodes accumulate) and double resident waves (up to
// 32/CU), so wall ~ 4 x T/2 = 2T with 2x the gather loads in flight.
__global__ __launch_bounds__(512) void bucket_gather(const uint2* __restrict__ hb2,
                                                     const int* __restrict__ binned,
                                                     const int* __restrict__ cursor,
                                                     const float* __restrict__ bias,
                                                     float4* __restrict__ out4) {
    __shared__ int cnt[BKT_NODES];
    __shared__ int pre[BKT_NODES];
    __shared__ int sEdge[BINCAP];
    const int t = threadIdx.x;
    const int b = blockIdx.x;
    if (t < BKT_NODES) cnt[t] = 0;
    __syncthreads();

    const int gbase = b * BINCAP;
    int sz = cursor[b];
    if (sz > BINCAP) sz = BINCAP;    // 11-sigma guard

    // rank edges per node (counting sort pass 1): 2560/512 = 5 iterations
    int pk[5], dd[5], rr[5];
#pragma unroll
    for (int it = 0; it < 5; ++it) {
        const int e = it * GT + t;
        if (e < sz) {
            const int p = binned[gbase + e];
            dd[it] = (p >> 17) & BKT_MASK;
            pk[it] = p & SRC_MASK;
            rr[it] = atomicAdd(&cnt[dd[it]], 1);
        } else dd[it] = -1;
    }
    __syncthreads();

    // inclusive scan of cnt[128]: per-wave shfl scan (waves 0-1), fixup
    if (t < 128) {
        int v = cnt[t];
#pragma unroll
        for (int s = 1; s < 64; s <<= 1) {
            const int u = __shfl_up(v, s);
            if ((t & 63) >= s) v += u;
        }
        pre[t] = v;
    }
    __syncthreads();
    if (t >= 64 && t < 128) pre[t] += pre[63];
    __syncthreads();

    // scatter into per-node segments: node d owns [pre[d]-cnt[d], pre[d])
#pragma unroll
    for (int it = 0; it < 5; ++it) {
        if (dd[it] >= 0)
            sEdge[pre[dd[it]] - cnt[dd[it]] + rr[it]] = pk[it];
    }
    __syncthreads();

    // accumulate: 32 quarter-waves, each owns 4 nodes; 8 loads in flight
    const int q  = t >> 4;           // quarter q owns nodes q*4..q*4+3
    const int c4 = t & 15;           // 8-byte column group (4 bf16 cols)
    const float4 bv = ((const float4*)bias)[c4];
#pragma unroll
    for (int i = 0; i < 4; ++i) {
        const int n    = q * 4 + i;
        const int node = b * BKT_NODES + n;
        if (node >= NN) break;       // uniform within quarter
        const int end = pre[n];
        float ax = 0.f, ay = 0.f, az = 0.f, aw = 0.f;
        for (int e = end - cnt[n]; e < end; e += 8) {
            uint2 x[8];
#pragma unroll
            for (int j = 0; j < 8; ++j) {
                const int idx = (e + j < end) ? sEdge[e + j] : -1;
                x[j] = (idx >= 0) ? hb2[(size_t)idx * 16 + c4] : make_uint2(0u, 0u);
            }
#pragma unroll
            for (int j = 0; j < 8; ++j) {
                ax += __uint_as_float(x[j].x << 16);
                ay += __uint_as_float(x[j].x & 0xFFFF0000u);
                az += __uint_as_float(x[j].y << 16);
                aw += __uint_as_float(x[j].y & 0xFFFF0000u);
            }
        }
        float4 v;
        v.x = ax + bv.x; v.y = ay + bv.y; v.z = az + bv.z; v.w = aw + bv.w;
        out4[(size_t)node * 16 + c4] = v;
    }
}

extern "C" void kernel_launch(void* const* d_in, const int* in_sizes, int n_in,
                              void* d_out, int out_size, void* d_ws, size_t ws_size,
                              hipStream_t stream) {
    const float* feat = (const float*)d_in[0];
    const int*   src  = (const int*)d_in[1];
    const int*   dst  = (const int*)d_in[2];
    const float* W    = (const float*)d_in[3];
    const float* bias = (const float*)d_in[4];
    float4* out = (float4*)d_out;

    // workspace layout (~20.8 MB)
    unsigned short* hb = (unsigned short*)d_ws;       // NN*D bf16 (12.8 MB)
    int* binned = (int*)(hb + (size_t)NN * D);        // NBKT*BINCAP (8.0 MB)
    int* cursor = binned + NBKT * BINCAP;             // NBKT counts

    seed_cursor<<<(NBKT + 255) / 256, 256, 0, stream>>>(cursor);
    fused_tp2<<<NPB + TGRID, 256, 0, stream>>>(feat, W, hb, src, dst, cursor, binned);
    bucket_gather<<<NBKT, GT, 0, stream>>>((const uint2*)hb, binned, cursor,
                                           bias, out);
}